// Round 4
// baseline (9816.335 us; speedup 1.0000x reference)
//
#include <hip/hip_runtime.h>
#include <hip/hip_cooperative_groups.h>

#define BB 64      // batch
#define TT 256     // time
#define EE 256     // embed dim
#define NU 1024    // hidden units
#define N3 3072    // 3*NU

static __device__ __forceinline__ const float* uniform_ptr(const float* p) {
    uint64_t v = (uint64_t)(uintptr_t)p;
    uint32_t lo = __builtin_amdgcn_readfirstlane((uint32_t)v);
    uint32_t hi = __builtin_amdgcn_readfirstlane((uint32_t)(v >> 32));
    return (const float*)(uintptr_t)(((uint64_t)hi << 32) | lo);
}

// ---------------------------------------------------------------------------
// Kernel 0a: pack U[k][g*NU+u] -> Upack[u*3+g][k]
// ---------------------------------------------------------------------------
__global__ __launch_bounds__(256) void upack_kernel(
    const float* __restrict__ U, float* __restrict__ up)
{
    __shared__ float t32[32][33];
    const int c0 = blockIdx.x * 32, k0 = blockIdx.y * 32;
    const int tx = threadIdx.x & 31, ty = threadIdx.x >> 5;
    #pragma unroll
    for (int i = 0; i < 4; ++i) {
        int k = ty + i * 8;
        t32[k][tx] = U[(size_t)(k0 + k) * N3 + c0 + tx];
    }
    __syncthreads();
    #pragma unroll
    for (int i = 0; i < 4; ++i) {
        int cl = ty + i * 8;
        int c = c0 + cl;
        int u = c & 1023, g = c >> 10;
        up[(size_t)(u * 3 + g) * NU + k0 + tx] = t32[tx][cl];
    }
}

// ---------------------------------------------------------------------------
// Kernel 0b: transpose tokens; 0c: init hT + zero barrier counters
// ---------------------------------------------------------------------------
__global__ __launch_bounds__(64) void tokT_kernel(
    const int* __restrict__ x, int* __restrict__ xT)
{
    const int t = blockIdx.x, b = threadIdx.x;
    xT[t * BB + b] = x[b * TT + t];
}

__global__ __launch_bounds__(256) void hinit_kernel(
    const float* __restrict__ hidden, float* __restrict__ hT, unsigned* __restrict__ cnt)
{
    const int u = blockIdx.x * 4 + (threadIdx.x >> 6);
    const int b = threadIdx.x & 63;
    hT[u * BB + b] = hidden[(size_t)b * NU + u];
    if (blockIdx.x == 0 && threadIdx.x < TT) cnt[threadIdx.x] = 0u;
}

// ---------------------------------------------------------------------------
// Kernel 1: xprojT[t][c][b] = (emb[x[b,t]] @ W + b0)[c]
// ---------------------------------------------------------------------------
__global__ __launch_bounds__(256) void xprojT_kernel(
    const int* __restrict__ x, const float* __restrict__ emb,
    const float* __restrict__ W, const float* __restrict__ bias,
    float* __restrict__ xpT)
{
    __shared__ float AsT[32][132];
    __shared__ float Ws[32][132];
    __shared__ int toks[128];

    const int tid = threadIdx.x;
    const int mt = blockIdx.x / 24, nt = blockIdx.x % 24;
    const int m0 = mt * 128, n0 = nt * 128;

    if (tid < 128) {
        int mg = m0 + tid;
        toks[tid] = x[(mg & 63) * TT + (mg >> 6)];
    }
    __syncthreads();

    const int tx = tid & 15, ty = tid >> 4;
    float acc[8][8] = {};

    for (int kb = 0; kb < 8; ++kb) {
        const int k0 = kb * 32;
        if (kb) __syncthreads();
        #pragma unroll
        for (int i = 0; i < 4; ++i) {
            int idx = tid + 256 * i;
            int m = idx >> 3, c4 = idx & 7;
            float4 av = *(const float4*)(emb + (size_t)toks[m] * EE + k0 + c4 * 4);
            AsT[c4 * 4 + 0][m] = av.x; AsT[c4 * 4 + 1][m] = av.y;
            AsT[c4 * 4 + 2][m] = av.z; AsT[c4 * 4 + 3][m] = av.w;
            int r = idx >> 5, w4 = idx & 31;
            *(float4*)&Ws[r][w4 * 4] =
                *(const float4*)(W + (size_t)(k0 + r) * N3 + n0 + w4 * 4);
        }
        __syncthreads();
        #pragma unroll 8
        for (int kk = 0; kk < 32; ++kk) {
            float a8[8], w8[8];
            *(float4*)a8       = *(const float4*)&AsT[kk][ty * 8];
            *(float4*)(a8 + 4) = *(const float4*)&AsT[kk][ty * 8 + 4];
            *(float4*)w8       = *(const float4*)&Ws[kk][tx * 8];
            *(float4*)(w8 + 4) = *(const float4*)&Ws[kk][tx * 8 + 4];
            #pragma unroll
            for (int i = 0; i < 8; ++i)
                #pragma unroll
                for (int j = 0; j < 8; ++j) acc[i][j] += a8[i] * w8[j];
        }
    }

    float b8[8];
    *(float4*)b8       = *(const float4*)(bias + n0 + tx * 8);
    *(float4*)(b8 + 4) = *(const float4*)(bias + n0 + tx * 8 + 4);
    const int t0 = mt * 2 + (ty >> 3);
    const int bb0 = (ty & 7) * 8;
    #pragma unroll
    for (int j = 0; j < 8; ++j) {
        const int c = n0 + tx * 8 + j;
        float4 lo, hi;
        lo.x = acc[0][j] + b8[j]; lo.y = acc[1][j] + b8[j];
        lo.z = acc[2][j] + b8[j]; lo.w = acc[3][j] + b8[j];
        hi.x = acc[4][j] + b8[j]; hi.y = acc[5][j] + b8[j];
        hi.z = acc[6][j] + b8[j]; hi.w = acc[7][j] + b8[j];
        size_t base = ((size_t)t0 * N3 + c) * BB + bb0;
        *(float4*)(xpT + base)     = lo;
        *(float4*)(xpT + base + 4) = hi;
    }
}

// ---------------------------------------------------------------------------
// Kernel 2: persistent GRU scan. 256 blocks x 512 threads (coop launch for
// co-residency; custom LLC barrier, NO grid.sync / NO cache flushes).
// Wave w = k-eighth; lane = batch; block owns units [u0,u0+4) = 12 streams.
// h crosses blocks via sc0sc1 (system-scope) LLC accesses only; U slices and
// xpT stay L1/L2-cached across all 256 steps. hold state lives in registers.
// ---------------------------------------------------------------------------
__global__ __launch_bounds__(512) void gru_persist(
    const int* __restrict__ xT, const float* __restrict__ upack,
    const float* __restrict__ bias, const float* __restrict__ xpT,
    float* __restrict__ out, const float* __restrict__ hidden,
    float* hf0, float* hf1, unsigned* cnt)
{
    __shared__ float red[8][12][64];   // 24 KB

    const int tid = threadIdx.x;
    const int u0 = blockIdx.x * 4;
    const int w = tid >> 6;            // k-eighth (0..7); also unit j for tid<256
    const int lane = tid & 63;         // batch

    // 12 uniform U streams for this wave: col (u0+du)*3+g, k-eighth w
    const float* up = uniform_ptr(upack + (size_t)u0 * 3 * NU + w * 128);

    // gating state (tid < 256): unit j = w, batch = lane
    float hold = 0.f, brz = 0.f, brr = 0.f, brh = 0.f;
    if (tid < 256) {
        hold = hidden[(size_t)lane * NU + u0 + w];
        brz = bias[N3 + 0 * NU + u0 + w];
        brr = bias[N3 + 1 * NU + u0 + w];
        brh = bias[N3 + 2 * NU + u0 + w];
    }
    float* state_out = out + (size_t)BB * TT * NU;

    const float* hc = hf0;
    float* hn = hf1;

    for (int t = 0; t < TT; ++t) {
        // ---- recurrent GEMM over this wave's k-eighth ----
        float acc[12] = {};
        const float* hq = hc + (size_t)w * 128 * BB;
        #pragma unroll 4
        for (int c = 0; c < 32; ++c) {
            float hv[4];
            #pragma unroll
            for (int kk = 0; kk < 4; ++kk)
                hv[kk] = __hip_atomic_load(
                    (const float*)&hq[(c * 4 + kk) * BB + lane],
                    __ATOMIC_RELAXED, __HIP_MEMORY_SCOPE_SYSTEM);
            #pragma unroll
            for (int s = 0; s < 12; ++s) {
                float4 u4 = *(const float4*)(up + s * NU + c * 4);
                acc[s] += u4.x * hv[0] + u4.y * hv[1] + u4.z * hv[2] + u4.w * hv[3];
            }
        }
        #pragma unroll
        for (int s = 0; s < 12; ++s) red[w][s][lane] = acc[s];
        __syncthreads();

        // ---- gating (tid < 256): unit u0+w, batch lane ----
        if (tid < 256) {
            const int j = w;
            float rz = brz, rr = brr, rh = brh;
            #pragma unroll
            for (int q = 0; q < 8; ++q) {
                rz += red[q][j * 3 + 0][lane];
                rr += red[q][j * 3 + 1][lane];
                rh += red[q][j * 3 + 2][lane];
            }
            size_t xb = ((size_t)t * N3 + u0 + j) * BB + lane;
            float xz = xpT[xb];
            float xr = xpT[xb + (size_t)NU * BB];
            float xh = xpT[xb + (size_t)2 * NU * BB];
            int tok = xT[t * BB + lane];

            float z  = 1.f / (1.f + expf(-(xz + rz)));
            float r  = 1.f / (1.f + expf(-(xr + rr)));
            float hh = tanhf(xh + r * rh);
            float hnew = z * hold + (1.f - z) * hh;
            if (tok == 0) hnew = hold;   // mask_zero: carry state

            __hip_atomic_store(&hn[(u0 + j) * BB + lane], hnew,
                               __ATOMIC_RELAXED, __HIP_MEMORY_SCOPE_SYSTEM);
            out[((size_t)lane * TT + t) * NU + u0 + j] = hnew;
            if (t == TT - 1) state_out[(size_t)lane * NU + u0 + j] = hnew;
            hold = hnew;
        }

        // ---- LLC barrier: all h stores drained, then arrive + spin ----
        __builtin_amdgcn_s_waitcnt(0);
        __syncthreads();
        if (tid == 0) {
            __hip_atomic_fetch_add(&cnt[t], 1u,
                                   __ATOMIC_RELAXED, __HIP_MEMORY_SCOPE_SYSTEM);
            unsigned v;
            long guard = 0;
            do {
                v = __hip_atomic_load(&cnt[t],
                                      __ATOMIC_RELAXED, __HIP_MEMORY_SCOPE_SYSTEM);
                if (v < 256u) __builtin_amdgcn_s_sleep(8);
            } while (v < 256u && ++guard < (1L << 24));
        }
        __syncthreads();

        float* tmp = (float*)hc; hc = hn; hn = tmp;
    }
}

// ---------------------------------------------------------------------------
extern "C" void kernel_launch(void* const* d_in, const int* in_sizes, int n_in,
                              void* d_out, int out_size, void* d_ws, size_t ws_size,
                              hipStream_t stream) {
    const int*   x      = (const int*)d_in[0];
    const float* hidden = (const float*)d_in[1];
    const float* emb    = (const float*)d_in[2];
    const float* W      = (const float*)d_in[3];
    const float* U      = (const float*)d_in[4];
    const float* bvec   = (const float*)d_in[5];

    float* out = (float*)d_out;

    float*    xpT   = (float*)d_ws;                       // 50,331,648 floats
    float*    upack = xpT + (size_t)16384 * N3;           //  3,145,728 floats
    float*    h0    = upack + (size_t)3 * NU * NU;        //     65,536 floats
    float*    h1    = h0 + (size_t)NU * BB;               //     65,536 floats
    int*      xT    = (int*)(h1 + (size_t)NU * BB);       //     16,384 ints
    unsigned* cnt   = (unsigned*)(xT + TT * BB);          //        256 uints

    upack_kernel<<<dim3(96, 32), dim3(256), 0, stream>>>(U, upack);
    tokT_kernel<<<dim3(TT), dim3(64), 0, stream>>>(x, xT);
    hinit_kernel<<<dim3(256), dim3(256), 0, stream>>>(hidden, h0, cnt);
    xprojT_kernel<<<dim3(3072), dim3(256), 0, stream>>>(x, emb, W, bvec, xpT);

    void* args[] = {(void*)&xT, (void*)&upack, (void*)&bvec, (void*)&xpT,
                    (void*)&out, (void*)&hidden, (void*)&h0, (void*)&h1,
                    (void*)&cnt};
    hipLaunchCooperativeKernel((const void*)gru_persist, dim3(256), dim3(512),
                               args, 0, stream);
}

// Round 5
// 7930.537 us; speedup vs baseline: 1.2378x; 1.2378x over previous
//
#include <hip/hip_runtime.h>
#include <hip/hip_cooperative_groups.h>

#define BB 64      // batch
#define TT 256     // time
#define EE 256     // embed dim
#define NU 1024    // hidden units
#define N3 3072    // 3*NU

// ---------------------------------------------------------------------------
// Kernel 0a: pack U[k][g*NU+u] -> Upack[u*3+g][k]
// ---------------------------------------------------------------------------
__global__ __launch_bounds__(256) void upack_kernel(
    const float* __restrict__ U, float* __restrict__ up)
{
    __shared__ float t32[32][33];
    const int c0 = blockIdx.x * 32, k0 = blockIdx.y * 32;
    const int tx = threadIdx.x & 31, ty = threadIdx.x >> 5;
    #pragma unroll
    for (int i = 0; i < 4; ++i) {
        int k = ty + i * 8;
        t32[k][tx] = U[(size_t)(k0 + k) * N3 + c0 + tx];
    }
    __syncthreads();
    #pragma unroll
    for (int i = 0; i < 4; ++i) {
        int cl = ty + i * 8;
        int c = c0 + cl;
        int u = c & 1023, g = c >> 10;
        up[(size_t)(u * 3 + g) * NU + k0 + tx] = t32[tx][cl];
    }
}

// ---------------------------------------------------------------------------
// Kernel 0b: transpose tokens; 0c: init hT (k-major) + zero barrier counters
// ---------------------------------------------------------------------------
__global__ __launch_bounds__(64) void tokT_kernel(
    const int* __restrict__ x, int* __restrict__ xT)
{
    const int t = blockIdx.x, b = threadIdx.x;
    xT[t * BB + b] = x[b * TT + t];
}

__global__ __launch_bounds__(256) void hinit_kernel(
    const float* __restrict__ hidden, float* __restrict__ hT, unsigned* __restrict__ cnt)
{
    const int u = blockIdx.x * 4 + (threadIdx.x >> 6);
    const int b = threadIdx.x & 63;
    hT[u * BB + b] = hidden[(size_t)b * NU + u];
    if (blockIdx.x == 0 && threadIdx.x < TT) cnt[threadIdx.x] = 0u;
}

// ---------------------------------------------------------------------------
// Kernel 1: xprojT[t][c][b] = (emb[x[b,t]] @ W + b0)[c]
// ---------------------------------------------------------------------------
__global__ __launch_bounds__(256) void xprojT_kernel(
    const int* __restrict__ x, const float* __restrict__ emb,
    const float* __restrict__ W, const float* __restrict__ bias,
    float* __restrict__ xpT)
{
    __shared__ float AsT[32][132];
    __shared__ float Ws[32][132];
    __shared__ int toks[128];

    const int tid = threadIdx.x;
    const int mt = blockIdx.x / 24, nt = blockIdx.x % 24;
    const int m0 = mt * 128, n0 = nt * 128;

    if (tid < 128) {
        int mg = m0 + tid;
        toks[tid] = x[(mg & 63) * TT + (mg >> 6)];
    }
    __syncthreads();

    const int tx = tid & 15, ty = tid >> 4;
    float acc[8][8] = {};

    for (int kb = 0; kb < 8; ++kb) {
        const int k0 = kb * 32;
        if (kb) __syncthreads();
        #pragma unroll
        for (int i = 0; i < 4; ++i) {
            int idx = tid + 256 * i;
            int m = idx >> 3, c4 = idx & 7;
            float4 av = *(const float4*)(emb + (size_t)toks[m] * EE + k0 + c4 * 4);
            AsT[c4 * 4 + 0][m] = av.x; AsT[c4 * 4 + 1][m] = av.y;
            AsT[c4 * 4 + 2][m] = av.z; AsT[c4 * 4 + 3][m] = av.w;
            int r = idx >> 5, w4 = idx & 31;
            *(float4*)&Ws[r][w4 * 4] =
                *(const float4*)(W + (size_t)(k0 + r) * N3 + n0 + w4 * 4);
        }
        __syncthreads();
        #pragma unroll 8
        for (int kk = 0; kk < 32; ++kk) {
            float a8[8], w8[8];
            *(float4*)a8       = *(const float4*)&AsT[kk][ty * 8];
            *(float4*)(a8 + 4) = *(const float4*)&AsT[kk][ty * 8 + 4];
            *(float4*)w8       = *(const float4*)&Ws[kk][tx * 8];
            *(float4*)(w8 + 4) = *(const float4*)&Ws[kk][tx * 8 + 4];
            #pragma unroll
            for (int i = 0; i < 8; ++i)
                #pragma unroll
                for (int j = 0; j < 8; ++j) acc[i][j] += a8[i] * w8[j];
        }
    }

    float b8[8];
    *(float4*)b8       = *(const float4*)(bias + n0 + tx * 8);
    *(float4*)(b8 + 4) = *(const float4*)(bias + n0 + tx * 8 + 4);
    const int t0 = mt * 2 + (ty >> 3);
    const int bb0 = (ty & 7) * 8;
    #pragma unroll
    for (int j = 0; j < 8; ++j) {
        const int c = n0 + tx * 8 + j;
        float4 lo, hi;
        lo.x = acc[0][j] + b8[j]; lo.y = acc[1][j] + b8[j];
        lo.z = acc[2][j] + b8[j]; lo.w = acc[3][j] + b8[j];
        hi.x = acc[4][j] + b8[j]; hi.y = acc[5][j] + b8[j];
        hi.z = acc[6][j] + b8[j]; hi.w = acc[7][j] + b8[j];
        size_t base = ((size_t)t0 * N3 + c) * BB + bb0;
        *(float4*)(xpT + base)     = lo;
        *(float4*)(xpT + base + 4) = hi;
    }
}

// ---------------------------------------------------------------------------
// Kernel 2: persistent GRU scan, 256 blocks x 512 threads (coop launch for
// co-residency). Coherence protocol:
//   - h stores: __hip_atomic_store RELAXED/SYSTEM  -> sc0 sc1 write-through
//     to LLC (no dirty L2 lines, LLC always fresh)   [proven in R4]
//   - h loads: PLAIN cached loads (L1/L2 hits, vector-pipelined)
//   - per step after barrier: acquire fence -> buffer_inv (L1+L2) so the
//     only mutable data (h) is re-fetched from LLC; 32 blocks/XCD share the
//     L2 refill. U lives in LDS (inv-immune); xpT/tokens are immutable.
// ---------------------------------------------------------------------------
__global__ __launch_bounds__(512) void gru_persist(
    const int* __restrict__ xT, const float* __restrict__ upack,
    const float* __restrict__ bias, const float* __restrict__ xpT,
    float* __restrict__ out, const float* __restrict__ hidden,
    float* hf0, float* hf1, unsigned* cnt)
{
    __shared__ float4 Us4[12][256];    // 48 KB: U streams, float4 over k
    __shared__ float red[8][12][64];   // 24 KB: per-wave k-partials

    const int tid = threadIdx.x;
    const int u0 = blockIdx.x * 4;
    const int w = tid >> 6;            // k-eighth; also unit j for tid<256
    const int lane = tid & 63;         // batch

    // preload U slice into LDS (streams s = du*3+g, global col u0*3+s)
    for (int i = tid; i < 12 * 256; i += 512) {
        int s = i >> 8, k4 = i & 255;
        Us4[s][k4] = *(const float4*)(upack + (size_t)(u0 * 3 + s) * NU + k4 * 4);
    }

    float hold = 0.f, brz = 0.f, brr = 0.f, brh = 0.f;
    if (tid < 256) {
        hold = hidden[(size_t)lane * NU + u0 + w];
        brz = bias[N3 + 0 * NU + u0 + w];
        brr = bias[N3 + 1 * NU + u0 + w];
        brh = bias[N3 + 2 * NU + u0 + w];
    }
    float* state_out = out + (size_t)BB * TT * NU;
    __syncthreads();

    const float* hc = hf0;
    float* hn = hf1;

    for (int t = 0; t < TT; ++t) {
        // ---- recurrent GEMM over this wave's k-eighth (h cached loads) ----
        float acc[12] = {};
        const float* hq = hc + (size_t)w * 128 * BB + lane;
        #pragma unroll 4
        for (int c = 0; c < 32; ++c) {
            float hv0 = hq[(c * 4 + 0) * BB];
            float hv1 = hq[(c * 4 + 1) * BB];
            float hv2 = hq[(c * 4 + 2) * BB];
            float hv3 = hq[(c * 4 + 3) * BB];
            #pragma unroll
            for (int s = 0; s < 12; ++s) {
                float4 u4 = Us4[s][w * 32 + c];
                acc[s] += u4.x * hv0 + u4.y * hv1 + u4.z * hv2 + u4.w * hv3;
            }
        }
        #pragma unroll
        for (int s = 0; s < 12; ++s) red[w][s][lane] = acc[s];
        __syncthreads();

        // ---- gating (tid < 256): unit u0+w, batch lane ----
        if (tid < 256) {
            const int j = w;
            float rz = brz, rr = brr, rh = brh;
            #pragma unroll
            for (int q = 0; q < 8; ++q) {
                rz += red[q][j * 3 + 0][lane];
                rr += red[q][j * 3 + 1][lane];
                rh += red[q][j * 3 + 2][lane];
            }
            size_t xb = ((size_t)t * N3 + u0 + j) * BB + lane;
            float xz = xpT[xb];
            float xr = xpT[xb + (size_t)NU * BB];
            float xh = xpT[xb + (size_t)2 * NU * BB];
            int tok = xT[t * BB + lane];

            float z  = 1.f / (1.f + expf(-(xz + rz)));
            float r  = 1.f / (1.f + expf(-(xr + rr)));
            float hh = tanhf(xh + r * rh);
            float hnew = z * hold + (1.f - z) * hh;
            if (tok == 0) hnew = hold;   // mask_zero: carry state

            // write-through stores (LLC-visible, no dirty L2 lines)
            __hip_atomic_store(&hn[(u0 + j) * BB + lane], hnew,
                               __ATOMIC_RELAXED, __HIP_MEMORY_SCOPE_SYSTEM);
            __hip_atomic_store(&out[((size_t)lane * TT + t) * NU + u0 + j], hnew,
                               __ATOMIC_RELAXED, __HIP_MEMORY_SCOPE_SYSTEM);
            if (t == TT - 1)
                __hip_atomic_store(&state_out[(size_t)lane * NU + u0 + j], hnew,
                                   __ATOMIC_RELAXED, __HIP_MEMORY_SCOPE_SYSTEM);
            hold = hnew;
        }

        // ---- barrier: drain WT stores, arrive, spin, acquire-inv ----
        __builtin_amdgcn_s_waitcnt(0);
        __syncthreads();
        if (tid == 0) {
            __hip_atomic_fetch_add(&cnt[t], 1u,
                                   __ATOMIC_RELAXED, __HIP_MEMORY_SCOPE_SYSTEM);
            unsigned v;
            long guard = 0;
            do {
                v = __hip_atomic_load(&cnt[t],
                                      __ATOMIC_RELAXED, __HIP_MEMORY_SCOPE_SYSTEM);
                if (v < 256u) __builtin_amdgcn_s_sleep(1);
            } while (v < 256u && ++guard < (1L << 24));
            // invalidate L1+L2 so next step's plain h loads re-fetch from LLC
            __builtin_amdgcn_fence(__ATOMIC_ACQUIRE, "");
        }
        __syncthreads();

        float* tmp = (float*)hc; hc = hn; hn = tmp;
    }
}

// ---------------------------------------------------------------------------
extern "C" void kernel_launch(void* const* d_in, const int* in_sizes, int n_in,
                              void* d_out, int out_size, void* d_ws, size_t ws_size,
                              hipStream_t stream) {
    const int*   x      = (const int*)d_in[0];
    const float* hidden = (const float*)d_in[1];
    const float* emb    = (const float*)d_in[2];
    const float* W      = (const float*)d_in[3];
    const float* U      = (const float*)d_in[4];
    const float* bvec   = (const float*)d_in[5];

    float* out = (float*)d_out;

    float*    xpT   = (float*)d_ws;                       // 50,331,648 floats
    float*    upack = xpT + (size_t)16384 * N3;           //  3,145,728 floats
    float*    h0    = upack + (size_t)3 * NU * NU;        //     65,536 floats
    float*    h1    = h0 + (size_t)NU * BB;               //     65,536 floats
    int*      xT    = (int*)(h1 + (size_t)NU * BB);       //     16,384 ints
    unsigned* cnt   = (unsigned*)(xT + TT * BB);          //        256 uints

    upack_kernel<<<dim3(96, 32), dim3(256), 0, stream>>>(U, upack);
    tokT_kernel<<<dim3(TT), dim3(64), 0, stream>>>(x, xT);
    hinit_kernel<<<dim3(256), dim3(256), 0, stream>>>(hidden, h0, cnt);
    xprojT_kernel<<<dim3(3072), dim3(256), 0, stream>>>(x, emb, W, bvec, xpT);

    void* args[] = {(void*)&xT, (void*)&upack, (void*)&bvec, (void*)&xpT,
                    (void*)&out, (void*)&hidden, (void*)&h0, (void*)&h1,
                    (void*)&cnt};
    hipLaunchCooperativeKernel((const void*)gru_persist, dim3(256), dim3(512),
                               args, 0, stream);
}